// Round 10
// baseline (210.185 us; speedup 1.0000x reference)
//
#include <hip/hip_runtime.h>
#include <stdint.h>

typedef __attribute__((ext_vector_type(8))) short bf16x8;
typedef __attribute__((ext_vector_type(4))) float f32x4;

#define HH  100   // history length
#define DD  128   // embedding dim d
#define HID 256   // hidden width / concat dim
#define NT  7     // m-tiles (112 rows >= 100)
#define NE  4     // elements per block

__device__ __forceinline__ unsigned short f2bf(float f) {
    unsigned int u = __float_as_uint(f);
    u += 0x7fffu + ((u >> 16) & 1u);   // RNE
    return (unsigned short)(u >> 16);
}

// Pack W1 (256x256 f32, [n][k]) into MFMA fragment order, bf16 (runs once).
// unit = (st*8+s)*64 + lane holds W1[st*16 + (lane&15)][s*32 + (lane>>4)*8 + j]
__global__ void w1_pack(const float* __restrict__ W1, unsigned short* __restrict__ W1p) {
    int unit = blockIdx.x * 256 + threadIdx.x;   // 0..8191
    int lane = unit & 63;
    int s    = (unit >> 6) & 7;
    int st   = unit >> 9;
    int col  = lane & 15, quad = lane >> 4;
    const float* src = W1 + (size_t)(st * 16 + col) * HID + s * 32 + quad * 8;
    union { unsigned short u[8]; bf16x8 v; } o;
    #pragma unroll
    for (int j = 0; j < 8; j++) o.u[j] = f2bf(src[j]);
    *(bf16x8*)(W1p + (size_t)unit * 8) = o.v;
}

// pure-VALU packed bf16 convert (no memory side effects — safe asm)
__device__ __forceinline__ unsigned int cvt_pk_bf16(float lo, float hi) {
    unsigned int r;   // r[15:0]=bf16(lo), r[31:16]=bf16(hi)
    asm("v_cvt_pk_bf16_f32 %0, %1, %2" : "=v"(r) : "v"(lo), "v"(hi));
    return r;
}

// multiply 2 float4 by tgt slice, accumulate xsum, cvt+store one A-frag s-step
#define CONSUME(V0, V1, S, AP, TGT, ACC) do {                                     \
    const float* tp_ = (TGT) + (S) * 32 + quad * 8;                               \
    float4 t0_ = *(const float4*)tp_, t1_ = *(const float4*)(tp_ + 4);            \
    float x0=(V0).x*t0_.x, x1=(V0).y*t0_.y, x2=(V0).z*t0_.z, x3=(V0).w*t0_.w;     \
    float x4=(V1).x*t1_.x, x5=(V1).y*t1_.y, x6=(V1).z*t1_.z, x7=(V1).w*t1_.w;     \
    (ACC) += (x0+x1)+(x2+x3)+((x4+x5)+(x6+x7));                                   \
    union { unsigned int u[4]; int4 v; } fb_;                                     \
    fb_.u[0]=cvt_pk_bf16(x0,x1); fb_.u[1]=cvt_pk_bf16(x2,x3);                     \
    fb_.u[2]=cvt_pk_bf16(x4,x5); fb_.u[3]=cvt_pk_bf16(x6,x7);                     \
    *(int4*)((AP) + (size_t)((S) * 64 + lane) * 8) = fb_.v;                       \
} while (0)

// r9 structure + three targeted changes:
//  1. grid-half desync: blocks in the 2nd half s_sleep ~5k cyc at start so the two
//     co-resident blocks per CU run ANTI-phase (r9 counters: MFMA idle 75% because
//     both blocks gather together and sweep together in lockstep).
//  2. w1f pinned to AGPRs ("+a") — MFMA reads A/B from AGPR natively (ISA §10);
//     frees the whole arch-VGPR file for the gather window (r9: "+v" pin ate all
//     128 arch regs -> 2.1 MB scratch).
//  3. 3 barriers/element: phase-3 is wave0-only in-register (hidx double-buffered)
//     and overlaps waves1-3 staging next element's meta; fmaxf/fmaf epilogue.
__global__ __launch_bounds__(256, 2) void nais_kernel(
    const int* __restrict__ history,           // [B,HH]
    const int* __restrict__ target,            // [B]
    const int* __restrict__ history_region,    // [B,HH]
    const int* __restrict__ target_region,     // [B]
    const float* __restrict__ target_distance, // [B]
    const float* __restrict__ E_hist,          // [item,128]
    const float* __restrict__ E_tgt,           // [item,128]
    const float* __restrict__ E_reg,           // [region,128]
    const float* __restrict__ E_dist,          // [16,128]
    const float* __restrict__ b1,              // [256]
    const float* __restrict__ w2,              // [256]
    const unsigned short* __restrict__ W1p,    // packed bf16 fragments (128 KB)
    float* __restrict__ out,                   // [B]
    int Btot)
{
    __shared__ __align__(16) unsigned short As[NT * 4096];   // 56 KB
    __shared__ __align__(16) float tgts[HID];
    __shared__ __align__(16) float b1s[HID];
    __shared__ __align__(16) float w2s[HID];
    __shared__ __align__(16) float scorep[4][112];
    __shared__ __align__(16) float xsum[112];
    __shared__ __align__(16) int   hidx2[2][HH];   // double-buffered (phase3 overlap)
    __shared__ __align__(16) int   hreg[HH];
    __shared__ float s_sumE;

    const int t    = threadIdx.x;                // 0..255
    const int lane = t & 63;
    const int wave = t >> 6;                     // 0..3
    const int col  = lane & 15;
    const int quad = lane >> 4;

    const int base = blockIdx.x * NE;

    // ---- desync: anti-phase the two co-resident blocks per CU ----
    if (blockIdx.x * 2 >= gridDim.x) __builtin_amdgcn_s_sleep(80);   // ~5k cyc

    // ---- block prologue: b1/w2, sum(E_dist[0]) ----
    if (wave == 3) {
        *(float4*)(b1s + lane * 4) = *(const float4*)(b1 + lane * 4);
        *(float4*)(w2s + lane * 4) = *(const float4*)(w2 + lane * 4);
    }
    if (wave == 1) {
        float v = E_dist[lane] + E_dist[64 + lane];
        #pragma unroll
        for (int off = 32; off; off >>= 1) v += __shfl_xor(v, off);
        if (lane == 0) s_sumE = v;
    }

    // ---- W1 fragments -> 128 AGPRs/wave (4 strips x 8 s), pinned once ----
    bf16x8 w1f[32];
    #pragma unroll
    for (int j = 0; j < 32; j++) {
        const int unit = ((wave * 4 + (j >> 3)) * 8 + (j & 7)) * 64 + lane;
        w1f[j] = *(const bf16x8*)(W1p + (size_t)unit * 8);
    }
    #pragma unroll
    for (int j = 0; j < 32; j++) asm volatile("" : "+a"(w1f[j]));   // AGPR pin

    __syncthreads();   // b1s/w2s ready

    // per-strip bias/w2 constants, hoisted out of the element loop
    f32x4 bbv[4], wwv[4];
    #pragma unroll
    for (int st = 0; st < 4; st++) {
        bbv[st] = *(const f32x4*)&b1s[(wave * 4 + st) * 16 + quad * 4];
        wwv[st] = *(const f32x4*)&w2s[(wave * 4 + st) * 16 + quad * 4];
    }

    #pragma unroll 1
    for (int e = 0; e < NE; e++) {
        const int b = base + e;
        if (b >= Btot) break;

        const int   tg    = target[b];
        const float tdist = target_distance[b];
        int* hB = &hidx2[e & 1][0];

        // ---- phase 0: stage indices + tgt vector (overlaps wave0's phase3(e-1):
        //      hidx2 write goes to the OTHER buffer; tgts/hreg unread by phase3) ----
        if (t < HH) {
            hB[t]   = history[b * HH + t];
            hreg[t] = history_region[b * HH + t];
        }
        if (wave == 2) {
            float4 v;
            if (lane < 32) v = *(const float4*)(E_tgt + (size_t)tg * DD + lane * 4);
            else           v = *(const float4*)(E_reg + (size_t)target_region[b] * DD + (lane - 32) * 4);
            *(float4*)(tgts + lane * 4) = v;
        }
        __syncthreads();   // B0

        // ---- phase 1: gather E-rows, build X-frags into As, xsum ----
        #pragma unroll 1
        for (int ti = 0; ti < 2; ti++) {
            const int tile = wave + ti * 4;
            if (tile >= NT) break;
            const int row = tile * 16 + col;
            const int rc  = (row < HH) ? row : row - 64;
            const int ih  = hB[rc];
            const int ir  = hreg[rc];
            const float* ph = E_hist + (size_t)ih * DD + quad * 8;
            const float* pr = E_reg  + (size_t)ir * DD + quad * 8;
            unsigned short* ap = &As[tile * 4096];
            float4 g[16];
            #pragma unroll
            for (int s = 0; s < 4; s++) {
                g[2*s]     = *(const float4*)(ph + s * 32);
                g[2*s + 1] = *(const float4*)(ph + s * 32 + 4);
                g[8 + 2*s] = *(const float4*)(pr + s * 32);
                g[9 + 2*s] = *(const float4*)(pr + s * 32 + 4);
            }
            float acc = 0.f;
            #pragma unroll
            for (int s = 0; s < 8; s++) CONSUME(g[2*s], g[2*s+1], s, ap, tgts, acc);
            float v = acc;
            v += __shfl_xor(v, 16);
            v += __shfl_xor(v, 32);
            if (quad == 0) xsum[row] = v;      // rows >= HH written, never read
        }
        __syncthreads();   // B1 — As complete

        // ---- phase 2: sweep 7 m-tiles x this wave's 4 n-strips ----
        #pragma unroll 1
        for (int i = 0; i < NT; i++) {
            int mt = wave * 2 + i; if (mt >= NT) mt -= NT;   // stagger start
            const unsigned short* ap = &As[mt * 4096];
            f32x4 c0 = {0,0,0,0}, c1 = {0,0,0,0}, c2 = {0,0,0,0}, c3 = {0,0,0,0};
            #pragma unroll
            for (int s = 0; s < 8; s++) {
                bf16x8 xf = *(const bf16x8*)(ap + (size_t)(s * 64 + lane) * 8);
                c0 = __builtin_amdgcn_mfma_f32_16x16x32_bf16(w1f[s],      xf, c0, 0, 0, 0);
                c1 = __builtin_amdgcn_mfma_f32_16x16x32_bf16(w1f[8 + s],  xf, c1, 0, 0, 0);
                c2 = __builtin_amdgcn_mfma_f32_16x16x32_bf16(w1f[16 + s], xf, c2, 0, 0, 0);
                c3 = __builtin_amdgcn_mfma_f32_16x16x32_bf16(w1f[24 + s], xf, c3, 0, 0, 0);
            }
            float sp = 0.f;
            #pragma unroll
            for (int r = 0; r < 4; r++) {
                sp = fmaf(fmaxf(c0[r] + bbv[0][r], 0.f), wwv[0][r], sp);
                sp = fmaf(fmaxf(c1[r] + bbv[1][r], 0.f), wwv[1][r], sp);
                sp = fmaf(fmaxf(c2[r] + bbv[2][r], 0.f), wwv[2][r], sp);
                sp = fmaf(fmaxf(c3[r] + bbv[3][r], 0.f), wwv[3][r], sp);
            }
            sp += __shfl_xor(sp, 16);
            sp += __shfl_xor(sp, 32);
            if (quad == 0) scorep[wave][mt * 16 + col] = sp;
        }
        __syncthreads();   // B2 — scorep/xsum ready

        // ---- phase 3: wave0-only, fully in-register (no B3; waves 1-3 run ahead
        //      into next element's phase-0 staging, which touches only the other
        //      hidx2 buffer / tgts / hreg — none read here) ----
        if (wave == 0) {
            const float dist = tdist * s_sumE;
            float s1 = 0.f, s2 = 0.f;
            #pragma unroll
            for (int hh = 0; hh < 2; hh++) {
                const int h = lane + hh * 64;
                if (h < HH) {
                    float sc = scorep[0][h] + scorep[1][h] + scorep[2][h] + scorep[3][h];
                    if (hB[h] != tg) {
                        float ev = expf(sc + dist);
                        s1 += ev;
                        s2 += ev * xsum[h];
                    }
                }
            }
            #pragma unroll
            for (int off = 32; off; off >>= 1) {
                s1 += __shfl_xor(s1, off);
                s2 += __shfl_xor(s2, off);
            }
            if (lane == 0) {
                float pred = s2 / sqrtf(s1);   // exp_sum^0.5 (BETA=0.5)
                out[b] = 1.f / (1.f + expf(-pred));
            }
        }
        // next iteration's B0 provides the barrier before gather(e+1) reads hB/hreg/tgts
    }
}

extern "C" void kernel_launch(void* const* d_in, const int* in_sizes, int n_in,
                              void* d_out, int out_size, void* d_ws, size_t ws_size,
                              hipStream_t stream) {
    const int*   history         = (const int*)d_in[0];
    const int*   target          = (const int*)d_in[1];
    const int*   history_region  = (const int*)d_in[2];
    const int*   target_region   = (const int*)d_in[3];
    const float* target_distance = (const float*)d_in[4];
    const float* E_hist          = (const float*)d_in[5];
    const float* E_tgt           = (const float*)d_in[6];
    const float* E_reg           = (const float*)d_in[7];
    const float* E_dist          = (const float*)d_in[8];
    const float* W1              = (const float*)d_in[9];
    const float* b1              = (const float*)d_in[10];
    const float* w2              = (const float*)d_in[11];

    unsigned short* W1p = (unsigned short*)d_ws;  // 131072 B
    const int B = in_sizes[1];

    const int grid = (B + NE - 1) / NE;           // 2048/4 = 512 = 2 blocks/CU

    w1_pack<<<32, 256, 0, stream>>>(W1, W1p);
    nais_kernel<<<grid, 256, 0, stream>>>(history, target, history_region, target_region,
                                          target_distance, E_hist, E_tgt, E_reg, E_dist,
                                          b1, w2, W1p, (float*)d_out, B);
}

// Round 11
// 179.623 us; speedup vs baseline: 1.1701x; 1.1701x over previous
//
#include <hip/hip_runtime.h>
#include <stdint.h>

typedef __attribute__((ext_vector_type(8))) short bf16x8;
typedef __attribute__((ext_vector_type(4))) float f32x4;

#define HH  100   // history length
#define DD  128   // embedding dim d
#define HID 256   // hidden width / concat dim
#define NT  7     // m-tiles (112 rows >= 100)
#define NE  4     // elements per block

__device__ __forceinline__ unsigned short f2bf(float f) {
    unsigned int u = __float_as_uint(f);
    u += 0x7fffu + ((u >> 16) & 1u);   // RNE
    return (unsigned short)(u >> 16);
}

// Pack W1 (256x256 f32, [n][k]) into MFMA fragment order, bf16 (runs once).
// unit = (st*8+s)*64 + lane holds W1[st*16 + (lane&15)][s*32 + (lane>>4)*8 + j]
__global__ void w1_pack(const float* __restrict__ W1, unsigned short* __restrict__ W1p) {
    int unit = blockIdx.x * 256 + threadIdx.x;   // 0..8191
    int lane = unit & 63;
    int s    = (unit >> 6) & 7;
    int st   = unit >> 9;
    int col  = lane & 15, quad = lane >> 4;
    const float* src = W1 + (size_t)(st * 16 + col) * HID + s * 32 + quad * 8;
    union { unsigned short u[8]; bf16x8 v; } o;
    #pragma unroll
    for (int j = 0; j < 8; j++) o.u[j] = f2bf(src[j]);
    *(bf16x8*)(W1p + (size_t)unit * 8) = o.v;
}

// pure-VALU packed bf16 convert (no memory side effects — safe asm)
__device__ __forceinline__ unsigned int cvt_pk_bf16(float lo, float hi) {
    unsigned int r;   // r[15:0]=bf16(lo), r[31:16]=bf16(hi)
    asm("v_cvt_pk_bf16_f32 %0, %1, %2" : "=v"(r) : "v"(lo), "v"(hi));
    return r;
}

// multiply 2 float4 by tgt slice, accumulate xsum, cvt+store one A-frag s-step
#define CONSUME(V0, V1, S, AP, TGT, ACC) do {                                     \
    const float* tp_ = (TGT) + (S) * 32 + quad * 8;                               \
    float4 t0_ = *(const float4*)tp_, t1_ = *(const float4*)(tp_ + 4);            \
    float x0=(V0).x*t0_.x, x1=(V0).y*t0_.y, x2=(V0).z*t0_.z, x3=(V0).w*t0_.w;     \
    float x4=(V1).x*t1_.x, x5=(V1).y*t1_.y, x6=(V1).z*t1_.z, x7=(V1).w*t1_.w;     \
    (ACC) += (x0+x1)+(x2+x3)+((x4+x5)+(x6+x7));                                   \
    union { unsigned int u[4]; int4 v; } fb_;                                     \
    fb_.u[0]=cvt_pk_bf16(x0,x1); fb_.u[1]=cvt_pk_bf16(x2,x3);                     \
    fb_.u[2]=cvt_pk_bf16(x4,x5); fb_.u[3]=cvt_pk_bf16(x6,x7);                     \
    *(int4*)((AP) + (size_t)((S) * 64 + lane) * 8) = fb_.v;                       \
} while (0)

// gather one 16-row m-tile of element slot MS into As, xsum2[XB]
#define GATHER_TILE(TILE, MS, XB) do {                                            \
    const int row_ = (TILE) * 16 + col;                                           \
    const int rc_  = (row_ < HH) ? row_ : row_ - 64;                              \
    const int ih_  = hidx4[MS][rc_];                                              \
    const int ir_  = hreg4[MS][rc_];                                              \
    const float* ph_ = E_hist + (size_t)ih_ * DD + quad * 8;                      \
    const float* pr_ = E_reg  + (size_t)ir_ * DD + quad * 8;                      \
    unsigned short* ap_ = &As[(TILE) * 4096];                                     \
    float4 g_[16];                                                                \
    _Pragma("unroll")                                                             \
    for (int s_ = 0; s_ < 4; s_++) {                                              \
        g_[2*s_]     = *(const float4*)(ph_ + s_ * 32);                           \
        g_[2*s_ + 1] = *(const float4*)(ph_ + s_ * 32 + 4);                       \
        g_[8 + 2*s_] = *(const float4*)(pr_ + s_ * 32);                           \
        g_[9 + 2*s_] = *(const float4*)(pr_ + s_ * 32 + 4);                       \
    }                                                                             \
    float acc_ = 0.f;                                                             \
    _Pragma("unroll")                                                             \
    for (int s_ = 0; s_ < 8; s_++) CONSUME(g_[2*s_], g_[2*s_+1], s_, ap_, &tgts4[MS][0], acc_); \
    float v_ = acc_;                                                              \
    v_ += __shfl_xor(v_, 16);                                                     \
    v_ += __shfl_xor(v_, 32);                                                     \
    if (quad == 0) xsum2[XB][row_] = v_;                                          \
} while (0)

// r9 (best: 60.7 us) with ONE structural change: 2 barriers/element.
//   prologue: ALL meta (hidx/hreg/tgt rows) for the NE elements staged once.
//   loop e:  [sweep(e)] B2 [gather(e+1) waves0-3 || softmax(e) wave0-in-register] B1
// softmax leaves the critical path; its expf VALU fills the gather's memory stalls.
// xsum double-buffered; scorep consumed before B1; As free after B2 (slot-disjoint).
__global__ __launch_bounds__(256, 2) void nais_kernel(
    const int* __restrict__ history,           // [B,HH]
    const int* __restrict__ target,            // [B]
    const int* __restrict__ history_region,    // [B,HH]
    const int* __restrict__ target_region,     // [B]
    const float* __restrict__ target_distance, // [B]
    const float* __restrict__ E_hist,          // [item,128]
    const float* __restrict__ E_tgt,           // [item,128]
    const float* __restrict__ E_reg,           // [region,128]
    const float* __restrict__ E_dist,          // [16,128]
    const float* __restrict__ b1,              // [256]
    const float* __restrict__ w2,              // [256]
    const unsigned short* __restrict__ W1p,    // packed bf16 fragments (128 KB)
    float* __restrict__ out,                   // [B]
    int Btot)
{
    __shared__ __align__(16) unsigned short As[NT * 4096];   // 56 KB
    __shared__ __align__(16) float tgts4[NE][HID];           // 4 KB
    __shared__ __align__(16) float b1s[HID];
    __shared__ __align__(16) float w2s[HID];
    __shared__ __align__(16) float scorep[4][112];
    __shared__ __align__(16) float xsum2[2][112];
    __shared__ __align__(16) int   hidx4[NE][HH];            // 1.6 KB
    __shared__ __align__(16) int   hreg4[NE][HH];
    __shared__ int   tgA[NE];
    __shared__ float tdA[NE];
    __shared__ float s_sumE;

    const int t    = threadIdx.x;                // 0..255
    const int lane = t & 63;
    const int wave = t >> 6;                     // 0..3
    const int col  = lane & 15;
    const int quad = lane >> 4;

    const int base = blockIdx.x * NE;
    int cnt = Btot - base;
    if (cnt <= 0) return;
    if (cnt > NE) cnt = NE;

    // ---- prologue: scalars, b1/w2, s_sumE, target rows, ALL element meta ----
    if (t < cnt) {
        tgA[t] = target[base + t];
        tdA[t] = target_distance[base + t];
    }
    if (wave == 3) {
        *(float4*)(b1s + lane * 4) = *(const float4*)(b1 + lane * 4);
        *(float4*)(w2s + lane * 4) = *(const float4*)(w2 + lane * 4);
    }
    if (wave == 1) {
        float v = E_dist[lane] + E_dist[64 + lane];
        #pragma unroll
        for (int off = 32; off; off >>= 1) v += __shfl_xor(v, off);
        if (lane == 0) s_sumE = v;
    }
    if (wave < cnt) {    // wave w stages element w's target vector (no tgA dep)
        const int tg2 = target[base + wave];
        const int tr2 = target_region[base + wave];
        float4 v;
        if (lane < 32) v = *(const float4*)(E_tgt + (size_t)tg2 * DD + lane * 4);
        else           v = *(const float4*)(E_reg + (size_t)tr2 * DD + (lane - 32) * 4);
        *(float4*)(&tgts4[wave][lane * 4]) = v;
    }
    #pragma unroll
    for (int e = 0; e < NE; e++) {
        if (e < cnt && t < HH) {
            hidx4[e][t] = history[(size_t)(base + e) * HH + t];
            hreg4[e][t] = history_region[(size_t)(base + e) * HH + t];
        }
    }

    // ---- W1 fragments -> 128 registers/wave (4 strips x 8 s), pinned once ----
    bf16x8 w1f[32];
    #pragma unroll
    for (int j = 0; j < 32; j++) {
        const int unit = ((wave * 4 + (j >> 3)) * 8 + (j & 7)) * 64 + lane;
        w1f[j] = *(const bf16x8*)(W1p + (size_t)unit * 8);
    }
    #pragma unroll
    for (int j = 0; j < 32; j++) asm volatile("" : "+v"(w1f[j]));

    __syncthreads();   // P1 — meta/tgts/b1s ready

    // per-strip bias/w2 constants, hoisted out of the element loop
    f32x4 bbv[4], wwv[4];
    #pragma unroll
    for (int st = 0; st < 4; st++) {
        bbv[st] = *(const f32x4*)&b1s[(wave * 4 + st) * 16 + quad * 4];
        wwv[st] = *(const f32x4*)&w2s[(wave * 4 + st) * 16 + quad * 4];
    }

    // ---- prologue gather e0: tiles w0:{0} w1:{1,4} w2:{2,5} w3:{3,6} ----
    if (wave == 0) { GATHER_TILE(0, 0, 0); }
    else {
        GATHER_TILE(wave, 0, 0);
        GATHER_TILE(wave + 3, 0, 0);
    }
    __syncthreads();   // B1 for e=0

    #pragma unroll 1
    for (int e = 0; e < cnt; e++) {
        // ---- region B: sweep(e) — 7 m-tiles x this wave's 4 n-strips ----
        #pragma unroll 1
        for (int i = 0; i < NT; i++) {
            int mt = wave * 2 + i; if (mt >= NT) mt -= NT;   // stagger start
            const unsigned short* ap = &As[mt * 4096];
            f32x4 c0 = {0,0,0,0}, c1 = {0,0,0,0}, c2 = {0,0,0,0}, c3 = {0,0,0,0};
            #pragma unroll
            for (int s = 0; s < 8; s++) {
                bf16x8 xf = *(const bf16x8*)(ap + (size_t)(s * 64 + lane) * 8);
                c0 = __builtin_amdgcn_mfma_f32_16x16x32_bf16(w1f[s],      xf, c0, 0, 0, 0);
                c1 = __builtin_amdgcn_mfma_f32_16x16x32_bf16(w1f[8 + s],  xf, c1, 0, 0, 0);
                c2 = __builtin_amdgcn_mfma_f32_16x16x32_bf16(w1f[16 + s], xf, c2, 0, 0, 0);
                c3 = __builtin_amdgcn_mfma_f32_16x16x32_bf16(w1f[24 + s], xf, c3, 0, 0, 0);
            }
            float sp = 0.f;
            #pragma unroll
            for (int r = 0; r < 4; r++) {
                sp = fmaf(fmaxf(c0[r] + bbv[0][r], 0.f), wwv[0][r], sp);
                sp = fmaf(fmaxf(c1[r] + bbv[1][r], 0.f), wwv[1][r], sp);
                sp = fmaf(fmaxf(c2[r] + bbv[2][r], 0.f), wwv[2][r], sp);
                sp = fmaf(fmaxf(c3[r] + bbv[3][r], 0.f), wwv[3][r], sp);
            }
            sp += __shfl_xor(sp, 16);
            sp += __shfl_xor(sp, 32);
            if (quad == 0) scorep[wave][mt * 16 + col] = sp;
        }
        __syncthreads();   // B2 — scorep ready; As free for rewrite

        // ---- region A: gather(e+1) || softmax(e) ----
        const bool gg = (e + 1 < cnt);
        const int  nb = (e + 1) & 1;            // xsum buffer for e+1
        if (wave == 0) {
            if (gg) { GATHER_TILE(0, e + 1, nb); }
            // softmax(e), fully in-register on wave 0
            const float dist = tdA[e] * s_sumE;
            const int   tg   = tgA[e];
            float s1 = 0.f, s2 = 0.f;
            #pragma unroll
            for (int hh = 0; hh < 2; hh++) {
                const int h = lane + hh * 64;
                if (h < HH) {
                    float sc = scorep[0][h] + scorep[1][h] + scorep[2][h] + scorep[3][h];
                    if (hidx4[e][h] != tg) {
                        float ev = expf(sc + dist);
                        s1 += ev;
                        s2 += ev * xsum2[e & 1][h];
                    }
                }
            }
            #pragma unroll
            for (int off = 32; off; off >>= 1) {
                s1 += __shfl_xor(s1, off);
                s2 += __shfl_xor(s2, off);
            }
            if (lane == 0) {
                float pred = s2 / sqrtf(s1);    // exp_sum^0.5 (BETA=0.5)
                out[base + e] = 1.f / (1.f + expf(-pred));
            }
        } else if (gg) {
            GATHER_TILE(wave, e + 1, nb);
            GATHER_TILE(wave + 3, e + 1, nb);
        }
        __syncthreads();   // B1 — As(e+1)/xsum ready; scorep free
    }
}

extern "C" void kernel_launch(void* const* d_in, const int* in_sizes, int n_in,
                              void* d_out, int out_size, void* d_ws, size_t ws_size,
                              hipStream_t stream) {
    const int*   history         = (const int*)d_in[0];
    const int*   target          = (const int*)d_in[1];
    const int*   history_region  = (const int*)d_in[2];
    const int*   target_region   = (const int*)d_in[3];
    const float* target_distance = (const float*)d_in[4];
    const float* E_hist          = (const float*)d_in[5];
    const float* E_tgt           = (const float*)d_in[6];
    const float* E_reg           = (const float*)d_in[7];
    const float* E_dist          = (const float*)d_in[8];
    const float* W1              = (const float*)d_in[9];
    const float* b1              = (const float*)d_in[10];
    const float* w2              = (const float*)d_in[11];

    unsigned short* W1p = (unsigned short*)d_ws;  // 131072 B
    const int B = in_sizes[1];

    const int grid = (B + NE - 1) / NE;           // 2048/4 = 512 = 2 blocks/CU

    w1_pack<<<32, 256, 0, stream>>>(W1, W1p);
    nais_kernel<<<grid, 256, 0, stream>>>(history, target, history_region, target_region,
                                          target_distance, E_hist, E_tgt, E_reg, E_dist,
                                          b1, w2, W1p, (float*)d_out, B);
}